// Round 3
// baseline (536.179 us; speedup 1.0000x reference)
//
#include <hip/hip_runtime.h>

// Output layout (float*, concatenated in reference return order):
//   z_q_out : 64*64*64*64 = 16,777,216 floats  @ [0, 16777216)
//   loss    : 1 float                          @ [16777216]
//   idx_out : 64*64*64   =    262,144 floats   @ [16777217, 17039361)
//   perplex : 1 float                          @ [17039361]
#define ZQ_OFF    0
#define LOSS_OFF  16777216
#define IDX_OFF   16777217
#define PERP_OFF  17039361

#define NPOINTS   262144      // B*H*W
#define NELEM     16777216    // B*C*H*W

// ws layout: [0,2048) float embnorm[512]; [2048,4096) int hist[512]; [4096,4104) double lossacc

// ---------------- kernel 0: codebook norms + zero accumulators ----------------
__global__ void prep_kernel(const float* __restrict__ emb,
                            float* __restrict__ embnorm,
                            int* __restrict__ hist,
                            double* __restrict__ lossacc) {
    int k = threadIdx.x;          // 512 threads, 1 block
    hist[k] = 0;
    const float* e = emb + (k << 6);
    float s = 0.f;
    #pragma unroll
    for (int d = 0; d < 64; ++d) s += e[d] * e[d];
    embnorm[k] = s;
    if (k == 0) *lossacc = 0.0;
}

// ---------------- kernel 1: argmin + z_q(STE) + idx + hist + loss partials ----------------
__global__ __launch_bounds__(256) void vq_kernel(const float* __restrict__ z,
                                                 const float* __restrict__ emb,
                                                 const float* __restrict__ embnorm,
                                                 float* __restrict__ out,
                                                 int* __restrict__ hist,
                                                 double* __restrict__ lossacc) {
    // 1024 blocks x 256 threads; thread = one (b,h,w) point; block = b fixed, 4 h-rows.
    const int bid = blockIdx.x;
    const int b  = bid >> 4;                 // 64 b values
    const int h  = ((bid & 15) << 2) + (threadIdx.x >> 6); // 4 rows per block
    const int w  = threadIdx.x & 63;

    // Load this point's 64-dim vector; lanes (w=0..63) are consecutive -> coalesced per channel.
    const float* zp = z + ((size_t)b << 18) + ((size_t)h << 6) + w;  // + c*4096
    float zv[64];
    float z2 = 0.f;
    #pragma unroll
    for (int d = 0; d < 64; ++d) {
        float v = zp[(size_t)d << 12];
        zv[d] = v;
        z2 += v * v;
    }

    // Sweep all 512 codes; emb addresses are wave-uniform -> expect s_load + v_fmac.
    float best = 3.4e38f;
    int   bidx = 0;
    for (int k0 = 0; k0 < 512; k0 += 4) {
        const float* e0 = emb + ((size_t)k0 << 6);
        float a0 = 0.f, a1 = 0.f, a2 = 0.f, a3 = 0.f;
        #pragma unroll
        for (int d = 0; d < 64; ++d) {
            float v = zv[d];
            a0 += v * e0[d];
            a1 += v * e0[d + 64];
            a2 += v * e0[d + 128];
            a3 += v * e0[d + 192];
        }
        // same formula as reference: ||z||^2 + ||e||^2 - 2 z.e
        float d0 = z2 + embnorm[k0    ] - 2.f * a0;
        float d1 = z2 + embnorm[k0 + 1] - 2.f * a1;
        float d2 = z2 + embnorm[k0 + 2] - 2.f * a2;
        float d3 = z2 + embnorm[k0 + 3] - 2.f * a3;
        // strict < in ascending k preserves first-min (reference argmin tie rule)
        if (d0 < best) { best = d0; bidx = k0;     }
        if (d1 < best) { best = d1; bidx = k0 + 1; }
        if (d2 < best) { best = d2; bidx = k0 + 2; }
        if (d3 < best) { best = d3; bidx = k0 + 3; }
    }

    // idx output (as float) + histogram
    const size_t pidx = ((size_t)b << 12) + ((size_t)h << 6) + w;
    __builtin_nontemporal_store((float)bidx, &out[IDX_OFF + pidx]);
    atomicAdd(&hist[bidx], 1);

    // z_q straight-through write + loss partial.
    // Replicate reference rounding: diff = e - z (fp32); out = z + diff (fp32); loss term = diff^2.
    const float* eb = emb + ((size_t)bidx << 6);
    float* zqout = out + ((size_t)b << 18) + ((size_t)h << 6) + w;
    float lsum = 0.f;
    #pragma unroll
    for (int d = 0; d < 64; ++d) {
        float e    = eb[d];            // gather (per-lane row), emb is L1/L2 resident
        float diff = e - zv[d];
        lsum += diff * diff;
        // nt store: don't let the 64 MB z_q stream evict emb from L1/L2
        __builtin_nontemporal_store(zv[d] + diff, &zqout[(size_t)d << 12]);
    }

    // block-reduce lsum -> one double atomic per block
    #pragma unroll
    for (int off = 32; off; off >>= 1) lsum += __shfl_down(lsum, off, 64);
    __shared__ float wsum[4];
    if ((threadIdx.x & 63) == 0) wsum[threadIdx.x >> 6] = lsum;
    __syncthreads();
    if (threadIdx.x == 0) {
        atomicAdd(lossacc, (double)(wsum[0] + wsum[1] + wsum[2] + wsum[3]));
    }
}

// ---------------- kernel 2: finalize loss + perplexity ----------------
__global__ void fin_kernel(const int* __restrict__ hist,
                           const double* __restrict__ lossacc,
                           float* __restrict__ out) {
    int k = threadIdx.x;   // 512 threads, 1 block
    float avg = (float)hist[k] * (1.0f / 262144.0f);   // exact: cnt / 2^18
    float t = avg * logf(avg + 1e-10f);
    #pragma unroll
    for (int off = 32; off; off >>= 1) t += __shfl_down(t, off, 64);
    __shared__ float s[8];
    if ((k & 63) == 0) s[k >> 6] = t;
    __syncthreads();
    if (k == 0) {
        float S = 0.f;
        #pragma unroll
        for (int i = 0; i < 8; ++i) S += s[i];
        out[PERP_OFF] = expf(-S);
        out[LOSS_OFF] = (float)(1.25 * (*lossacc) / (double)NELEM);
    }
}

extern "C" void kernel_launch(void* const* d_in, const int* in_sizes, int n_in,
                              void* d_out, int out_size, void* d_ws, size_t ws_size,
                              hipStream_t stream) {
    const float* z   = (const float*)d_in[0];
    const float* emb = (const float*)d_in[1];
    float* out = (float*)d_out;

    float*  embnorm = (float*)d_ws;
    int*    hist    = (int*)((char*)d_ws + 2048);
    double* lossacc = (double*)((char*)d_ws + 4096);

    prep_kernel<<<1, 512, 0, stream>>>(emb, embnorm, hist, lossacc);
    vq_kernel<<<1024, 256, 0, stream>>>(z, emb, embnorm, out, hist, lossacc);
    fin_kernel<<<1, 512, 0, stream>>>(hist, lossacc, out);
}

// Round 5
// 527.880 us; speedup vs baseline: 1.0157x; 1.0157x over previous
//
#include <hip/hip_runtime.h>

// Output layout (float*, concatenated in reference return order):
//   z_q_out : 64*64*64*64 = 16,777,216 floats  @ [0, 16777216)
//   loss    : 1 float                          @ [16777216]
//   idx_out : 64*64*64   =    262,144 floats   @ [16777217, 17039361)
//   perplex : 1 float                          @ [17039361]
#define ZQ_OFF    0
#define LOSS_OFF  16777216
#define IDX_OFF   16777217
#define PERP_OFF  17039361

#define NPOINTS   262144      // B*H*W
#define NELEM     16777216    // B*C*H*W

// ws layout: [0,2048) float embnorm[512]; [2048,4096) int hist[512]; [4096,4104) double lossacc

// ---------------- kernel 0: codebook norms + zero accumulators ----------------
__global__ void prep_kernel(const float* __restrict__ emb,
                            float* __restrict__ embnorm,
                            int* __restrict__ hist,
                            double* __restrict__ lossacc) {
    int k = threadIdx.x;          // 512 threads, 1 block
    hist[k] = 0;
    const float* e = emb + (k << 6);
    float s = 0.f;
    #pragma unroll
    for (int d = 0; d < 64; ++d) s += e[d] * e[d];
    embnorm[k] = s;
    if (k == 0) *lossacc = 0.0;
}

// ---------------- kernel 1: argmin + z_q(STE) + idx + hist + loss partials ----------------
// __launch_bounds__(256, 4): 4 waves/SIMD min -> VGPR cap 128. Round-3 profile
// showed VGPR_Count=60 (< the 64 needed for zv[] residency) -> compiler
// rematerialized zv inside the 512-code sweep -> VALUBusy 64%, dur 475us.
__global__ __launch_bounds__(256, 4) void vq_kernel(const float* __restrict__ z,
                                                 const float* __restrict__ emb,
                                                 const float* __restrict__ embnorm,
                                                 float* __restrict__ out,
                                                 int* __restrict__ hist,
                                                 double* __restrict__ lossacc) {
    // 1024 blocks x 256 threads; thread = one (b,h,w) point; block = b fixed, 4 h-rows.
    const int bid = blockIdx.x;
    const int b  = bid >> 4;                 // 64 b values
    const int h  = ((bid & 15) << 2) + (threadIdx.x >> 6); // 4 rows per block
    const int w  = threadIdx.x & 63;

    // Load this point's 64-dim vector; lanes (w=0..63) are consecutive -> coalesced per channel.
    const float* zp = z + ((size_t)b << 18) + ((size_t)h << 6) + w;  // + c*4096
    float zv[64];
    float z2 = 0.f;
    #pragma unroll
    for (int d = 0; d < 64; ++d) {
        float v = zp[(size_t)d << 12];
        zv[d] = v;
        z2 += v * v;
    }

    // Sweep all 512 codes; emb addresses are wave-uniform -> expect s_load + v_fmac.
    float best = 3.4e38f;
    int   bidx = 0;
    for (int k0 = 0; k0 < 512; k0 += 4) {
        const float* e0 = emb + ((size_t)k0 << 6);
        float a0 = 0.f, a1 = 0.f, a2 = 0.f, a3 = 0.f;
        #pragma unroll
        for (int d = 0; d < 64; ++d) {
            float v = zv[d];
            a0 += v * e0[d];
            a1 += v * e0[d + 64];
            a2 += v * e0[d + 128];
            a3 += v * e0[d + 192];
        }
        // same formula as reference: ||z||^2 + ||e||^2 - 2 z.e
        float d0 = z2 + embnorm[k0    ] - 2.f * a0;
        float d1 = z2 + embnorm[k0 + 1] - 2.f * a1;
        float d2 = z2 + embnorm[k0 + 2] - 2.f * a2;
        float d3 = z2 + embnorm[k0 + 3] - 2.f * a3;
        // strict < in ascending k preserves first-min (reference argmin tie rule)
        if (d0 < best) { best = d0; bidx = k0;     }
        if (d1 < best) { best = d1; bidx = k0 + 1; }
        if (d2 < best) { best = d2; bidx = k0 + 2; }
        if (d3 < best) { best = d3; bidx = k0 + 3; }
    }

    // idx output (as float) + histogram
    const size_t pidx = ((size_t)b << 12) + ((size_t)h << 6) + w;
    __builtin_nontemporal_store((float)bidx, &out[IDX_OFF + pidx]);
    atomicAdd(&hist[bidx], 1);

    // z_q straight-through write + loss partial.
    // Replicate reference rounding: diff = e - z (fp32); out = z + diff (fp32); loss term = diff^2.
    const float* eb = emb + ((size_t)bidx << 6);
    float* zqout = out + ((size_t)b << 18) + ((size_t)h << 6) + w;
    float lsum = 0.f;
    #pragma unroll
    for (int d = 0; d < 64; ++d) {
        float e    = eb[d];            // gather (per-lane row), emb is L1/L2 resident
        float diff = e - zv[d];
        lsum += diff * diff;
        // nt store: don't let the 64 MB z_q stream evict emb from L1/L2
        __builtin_nontemporal_store(zv[d] + diff, &zqout[(size_t)d << 12]);
    }

    // block-reduce lsum -> one double atomic per block
    #pragma unroll
    for (int off = 32; off; off >>= 1) lsum += __shfl_down(lsum, off, 64);
    __shared__ float wsum[4];
    if ((threadIdx.x & 63) == 0) wsum[threadIdx.x >> 6] = lsum;
    __syncthreads();
    if (threadIdx.x == 0) {
        atomicAdd(lossacc, (double)(wsum[0] + wsum[1] + wsum[2] + wsum[3]));
    }
}

// ---------------- kernel 2: finalize loss + perplexity ----------------
__global__ void fin_kernel(const int* __restrict__ hist,
                           const double* __restrict__ lossacc,
                           float* __restrict__ out) {
    int k = threadIdx.x;   // 512 threads, 1 block
    float avg = (float)hist[k] * (1.0f / 262144.0f);   // exact: cnt / 2^18
    float t = avg * logf(avg + 1e-10f);
    #pragma unroll
    for (int off = 32; off; off >>= 1) t += __shfl_down(t, off, 64);
    __shared__ float s[8];
    if ((k & 63) == 0) s[k >> 6] = t;
    __syncthreads();
    if (k == 0) {
        float S = 0.f;
        #pragma unroll
        for (int i = 0; i < 8; ++i) S += s[i];
        out[PERP_OFF] = expf(-S);
        out[LOSS_OFF] = (float)(1.25 * (*lossacc) / (double)NELEM);
    }
}

extern "C" void kernel_launch(void* const* d_in, const int* in_sizes, int n_in,
                              void* d_out, int out_size, void* d_ws, size_t ws_size,
                              hipStream_t stream) {
    const float* z   = (const float*)d_in[0];
    const float* emb = (const float*)d_in[1];
    float* out = (float*)d_out;

    float*  embnorm = (float*)d_ws;
    int*    hist    = (int*)((char*)d_ws + 2048);
    double* lossacc = (double*)((char*)d_ws + 4096);

    prep_kernel<<<1, 512, 0, stream>>>(emb, embnorm, hist, lossacc);
    vq_kernel<<<1024, 256, 0, stream>>>(z, emb, embnorm, out, hist, lossacc);
    fin_kernel<<<1, 512, 0, stream>>>(hist, lossacc, out);
}